// Round 17
// baseline (1684.793 us; speedup 1.0000x reference)
//
#include <hip/hip_runtime.h>
#include <hip/hip_bf16.h>
#include <math.h>

// B=16, T=512, E=384, H=8, D=48, L=8, V=20000, FF=1536, M = B*T = 8192
#define M_ROWS 8192
#define E_DIM 384
#define FF_DIM 1536
#define V_DIM 20000
#define VPAD 20096   // 157 * 128
#define N_LAYER 8
#define QK_SCALE 0.14433756729740643f
#define PSTRIDE 320   // padded 314 partials per row
#define NPART 314

typedef __bf16 bf16x8 __attribute__((ext_vector_type(8)));
typedef short  s16x8  __attribute__((ext_vector_type(8)));
typedef float  f32x4  __attribute__((ext_vector_type(4)));
typedef __hip_bfloat16 bf16_t;

__device__ __forceinline__ void gl2lds16(const void* g, void* l) {
    __builtin_amdgcn_global_load_lds((const __attribute__((address_space(1))) void*)g,
                                     (__attribute__((address_space(3))) void*)l, 16, 0, 0);
}
__device__ __forceinline__ unsigned short bf16bits(float v) {
    return __builtin_bit_cast(unsigned short, __float2bfloat16(v));
}

// ---------------- weight prep ----------------
__global__ __launch_bounds__(256) void tconv_kernel(
    const float* __restrict__ in, bf16_t* __restrict__ out,
    int K, int N, int outRows, int rowoff)
{
    __shared__ float tile[32][33];
    const int n0 = blockIdx.x * 32, k0 = blockIdx.y * 32;
    const float* ip = in + (size_t)blockIdx.z * K * N;
    bf16_t* op = out + (size_t)blockIdx.z * outRows * K;
    const int tx = threadIdx.x & 31, ty = threadIdx.x >> 5;
#pragma unroll
    for (int i = 0; i < 32; i += 8)
        tile[ty + i][tx] = ip[(size_t)(k0 + ty + i) * N + n0 + tx];
    __syncthreads();
#pragma unroll
    for (int i = 0; i < 32; i += 8)
        op[(size_t)(rowoff + n0 + ty + i) * K + k0 + tx] = __float2bfloat16(tile[tx][ty + i]);
}

__global__ __launch_bounds__(256) void tokconv_kernel(
    const float* __restrict__ tok, bf16_t* __restrict__ out)
{
    const int total = VPAD * 48;  // groups of 8 cols
    for (int idx = blockIdx.x * 256 + threadIdx.x; idx < total; idx += gridDim.x * 256) {
        int row = idx / 48, gc = idx - row * 48;
        int col = gc * 8;
        s16x8 pk = {};
        if (row < V_DIM) {
            const float* tp = tok + (size_t)row * E_DIM + col;
            float4 f0 = *(const float4*)tp;
            float4 f1 = *(const float4*)(tp + 4);
            pk[0] = (short)bf16bits(f0.x); pk[1] = (short)bf16bits(f0.y);
            pk[2] = (short)bf16bits(f0.z); pk[3] = (short)bf16bits(f0.w);
            pk[4] = (short)bf16bits(f1.x); pk[5] = (short)bf16bits(f1.y);
            pk[6] = (short)bf16bits(f1.z); pk[7] = (short)bf16bits(f1.w);
        }
        *(s16x8*)&out[(size_t)row * E_DIM + col] = pk;
    }
}

__global__ __launch_bounds__(256) void bqkv_kernel(
    const float* __restrict__ bq, const float* __restrict__ bk,
    const float* __restrict__ bv, float* __restrict__ o)
{
    int i = blockIdx.x * 256 + threadIdx.x;
    if (i < N_LAYER * 1152) {
        int l = i / 1152, c = i - l * 1152;
        float v = (c < 384) ? bq[l * 384 + c] : (c < 768) ? bk[l * 384 + c - 384] : bv[l * 384 + c - 768];
        o[i] = v;
    }
}

// ---------------- embedding ----------------
__global__ __launch_bounds__(256) void embed_kernel(
    const int* __restrict__ idx, const float* __restrict__ tok,
    const float* __restrict__ pos, float* __restrict__ x)
{
    int row = blockIdx.x * 4 + (threadIdx.x >> 6);
    int lane = threadIdx.x & 63;
    int t = row & 511;
    int id = idx[row];
    const float* tr = tok + (size_t)id * E_DIM;
    const float* pr = pos + (size_t)t * E_DIM;
    float* xr = x + (size_t)row * E_DIM;
#pragma unroll
    for (int i = 0; i < 6; i++) { int c = lane + i * 64; xr[c] = tr[c] + pr[c]; }
}

// ---------------- layernorm -> bf16 ----------------
__global__ __launch_bounds__(256) void ln_kernel(
    const float* __restrict__ x, const float* __restrict__ g,
    const float* __restrict__ b, bf16_t* __restrict__ out)
{
    int row = blockIdx.x * 4 + (threadIdx.x >> 6);
    int lane = threadIdx.x & 63;
    const float* xr = x + (size_t)row * E_DIM;
    float vals[6];
    float s = 0.f;
#pragma unroll
    for (int i = 0; i < 6; i++) { vals[i] = xr[lane + i * 64]; s += vals[i]; }
#pragma unroll
    for (int off = 1; off < 64; off <<= 1) s += __shfl_xor(s, off);
    float mu = s * (1.f / E_DIM);
    float sq = 0.f;
#pragma unroll
    for (int i = 0; i < 6; i++) { float d = vals[i] - mu; sq += d * d; }
#pragma unroll
    for (int off = 1; off < 64; off <<= 1) sq += __shfl_xor(sq, off);
    float rstd = rsqrtf(sq * (1.f / E_DIM) + 1e-5f);
    bf16_t* orow = out + (size_t)row * E_DIM;
#pragma unroll
    for (int i = 0; i < 6; i++) {
        int c = lane + i * 64;
        orow[c] = __float2bfloat16((vals[i] - mu) * rstd * g[c] + b[c]);
    }
}

// ---------------- bf16 MFMA GEMM (3-buffer, counted-vmcnt pipeline) ----------------
// C[M,Ncols] = op(A[M,K] @ Bt[Npad,K]^T + bias).  BM = MREP*32.  Always swapped:
// mfma(B,A) -> lane reg-quad = 4 consecutive COLUMNS of one row.
// MODE 1: fp32 out += C (residual, float4 RMW)   MODE 2: bf16 out, GELU (ushort4)
// MODE 3: logits + fused sumexp; LDS-transposed coalesced store epilogue
// MODE 4: QKV epilogue -> qkvb bf16 (q pre-scaled) + V^T into C2 [16][384][512]
template <int MODE, int MREP>
__global__ __launch_bounds__(256) void gemm_kernel(
    const bf16_t* __restrict__ A, const bf16_t* __restrict__ Bt,
    const float* __restrict__ bias, void* __restrict__ Cv, void* __restrict__ C2,
    int Ncols, int K)
{
    constexpr int BMR = MREP * 32;
    constexpr int ASH = BMR * 32;
    constexpr int BUFSH = ASH + 4096;
    constexpr int NLD = MREP / 2 + 2;
    __shared__ __align__(16) short smem[3 * BUFSH];
    const int t = threadIdx.x;
    const int w = t >> 6, lane = t & 63;
    const int wm = w >> 1, wn = w & 1;
    const int bm = (MODE == 3 ? blockIdx.x : blockIdx.y) * BMR;
    const int bn = (MODE == 3 ? blockIdx.y : blockIdx.x) * 128;

    f32x4 acc[MREP][4];
#pragma unroll
    for (int m = 0; m < MREP; m++)
#pragma unroll
        for (int n = 0; n < 4; n++)
            acc[m][n] = (f32x4){0.f, 0.f, 0.f, 0.f};

    const int lg = lane >> 4;
    const int ll = lane & 15;
    const int nt = K / 32;

    auto stagef = [&](int kt, int buf) {
        short* sA = smem + buf * BUFSH;
        short* sB = sA + ASH;
#pragma unroll
        for (int i = 0; i < MREP / 2; i++) {
            int li = i * 256 + t;
            int g = li >> (MREP == 4 ? 7 : 6);
            int row = li & (BMR - 1);
            gl2lds16(A + (size_t)(bm + row) * K + kt + g * 8,
                     sA + (size_t)(i * 256 + w * 64) * 8);
        }
#pragma unroll
        for (int i = 0; i < 2; i++) {
            int li = i * 256 + t;
            gl2lds16(Bt + (size_t)(bn + (li & 127)) * K + kt + (li >> 7) * 8,
                     sB + (size_t)(i * 256 + w * 64) * 8);
        }
    };

    stagef(0, 0);
    stagef(32, 1);

    for (int tt = 0; tt < nt; ++tt) {
        if (tt + 2 < nt) {
            stagef((tt + 2) * 32, (tt + 2) % 3);
            asm volatile("s_waitcnt vmcnt(%0)" :: "n"(2 * NLD) : "memory");
        } else if (tt + 1 < nt) {
            asm volatile("s_waitcnt vmcnt(%0)" :: "n"(NLD) : "memory");
        } else {
            asm volatile("s_waitcnt vmcnt(0)" ::: "memory");
        }
        __builtin_amdgcn_s_barrier();

        const short* sA = smem + (tt % 3) * BUFSH;
        const short* sB = sA + ASH;
        bf16x8 af[MREP], bfr[4];
#pragma unroll
        for (int m = 0; m < MREP; m++)
            af[m] = __builtin_bit_cast(bf16x8,
                *(const s16x8*)&sA[(lg * BMR + wm * (BMR / 2) + m * 16 + ll) * 8]);
#pragma unroll
        for (int n = 0; n < 4; n++)
            bfr[n] = __builtin_bit_cast(bf16x8,
                *(const s16x8*)&sB[(lg * 128 + wn * 64 + n * 16 + ll) * 8]);
#pragma unroll
        for (int m = 0; m < MREP; m++)
#pragma unroll
            for (int n = 0; n < 4; n++)
                acc[m][n] = __builtin_amdgcn_mfma_f32_16x16x32_bf16(bfr[n], af[m], acc[m][n], 0, 0, 0);

        __builtin_amdgcn_s_barrier();
    }

    const int rowm0 = bm + wm * (BMR / 2) + ll;
    const int coln0 = bn + wn * 64 + lg * 4;

    if constexpr (MODE == 4) {
        if (bn < 768) {
            bf16_t* qkvb = (bf16_t*)Cv;
            const float sc = (bn >= 384) ? 1.f : QK_SCALE;
#pragma unroll
            for (int n = 0; n < 4; n++) {
                const int coln = coln0 + n * 16;
                const float4 b4 = *(const float4*)&bias[coln];
#pragma unroll
                for (int m = 0; m < MREP; m++) {
                    const int row = rowm0 + m * 16;
                    ushort4 pk;
                    pk.x = bf16bits((acc[m][n][0] + b4.x) * sc);
                    pk.y = bf16bits((acc[m][n][1] + b4.y) * sc);
                    pk.z = bf16bits((acc[m][n][2] + b4.z) * sc);
                    pk.w = bf16bits((acc[m][n][3] + b4.w) * sc);
                    *(ushort4*)&qkvb[(size_t)row * 1152 + coln] = pk;
                }
            }
        } else {
            bf16_t* vtb = (bf16_t*)C2;
            const int cc0 = coln0 - 768;
#pragma unroll
            for (int n = 0; n < 4; n++) {
                const float4 b4 = *(const float4*)&bias[coln0 + n * 16];
#pragma unroll
                for (int m = 0; m < MREP; m++) {
                    const int row = rowm0 + m * 16;
                    const int bb = row >> 9, tt2 = row & 511;
                    bf16_t* vb = vtb + (size_t)bb * 384 * 512 + tt2;
                    vb[(size_t)(cc0 + n * 16 + 0) * 512] = __float2bfloat16(acc[m][n][0] + b4.x);
                    vb[(size_t)(cc0 + n * 16 + 1) * 512] = __float2bfloat16(acc[m][n][1] + b4.y);
                    vb[(size_t)(cc0 + n * 16 + 2) * 512] = __float2bfloat16(acc[m][n][2] + b4.z);
                    vb[(size_t)(cc0 + n * 16 + 3) * 512] = __float2bfloat16(acc[m][n][3] + b4.w);
                }
            }
        }
    } else if constexpr (MODE == 1) {
        float* C = (float*)Cv;
#pragma unroll
        for (int n = 0; n < 4; n++) {
            const int coln = coln0 + n * 16;
            const float4 b4 = *(const float4*)&bias[coln];
#pragma unroll
            for (int m = 0; m < MREP; m++) {
                const int row = rowm0 + m * 16;
                float4 cv = *(float4*)&C[(size_t)row * Ncols + coln];
                cv.x += acc[m][n][0] + b4.x;
                cv.y += acc[m][n][1] + b4.y;
                cv.z += acc[m][n][2] + b4.z;
                cv.w += acc[m][n][3] + b4.w;
                *(float4*)&C[(size_t)row * Ncols + coln] = cv;
            }
        }
    } else if constexpr (MODE == 2) {
        bf16_t* O = (bf16_t*)Cv;
#pragma unroll
        for (int n = 0; n < 4; n++) {
            const int coln = coln0 + n * 16;
            const float4 b4 = *(const float4*)&bias[coln];
#pragma unroll
            for (int m = 0; m < MREP; m++) {
                const int row = rowm0 + m * 16;
                float v0 = acc[m][n][0] + b4.x, v1 = acc[m][n][1] + b4.y;
                float v2 = acc[m][n][2] + b4.z, v3 = acc[m][n][3] + b4.w;
                v0 = 0.5f * v0 * (1.f + erff(v0 * 0.70710678118654752f));
                v1 = 0.5f * v1 * (1.f + erff(v1 * 0.70710678118654752f));
                v2 = 0.5f * v2 * (1.f + erff(v2 * 0.70710678118654752f));
                v3 = 0.5f * v3 * (1.f + erff(v3 * 0.70710678118654752f));
                ushort4 pk;
                pk.x = bf16bits(v0); pk.y = bf16bits(v1);
                pk.z = bf16bits(v2); pk.w = bf16bits(v3);
                *(ushort4*)&O[(size_t)row * Ncols + coln] = pk;
            }
        }
    } else if constexpr (MODE == 3) {
        // LDS-transposed coalesced epilogue: per 64-row half, pass1 writes
        // bias-added values into padded [64][133] f32 LDS (+ fused sumexp);
        // pass2 streams full 512B row segments (32 lanes = 1 row) with NT.
        float* C = (float*)Cv;
        float* pbuf = (float*)C2;
        float* LDSf = (float*)smem;   // 64*133*4 = 34 KB <= 48 KB
        const int ptile = blockIdx.y * 2 + wn;
        const int lr0 = t >> 5;        // 0..7
        const int lc = (t & 31) * 4;   // col offset in 128-wide tile

        for (int h = 0; h < 2; ++h) {
            __builtin_amdgcn_s_barrier();
            if (wm == h) {
#pragma unroll
                for (int m = 0; m < MREP; m++) {
                    const int row = rowm0 + m * 16;
                    const int lrow = m * 16 + ll;
                    float se = 0.f;
#pragma unroll
                    for (int n = 0; n < 4; n++) {
                        const int coln = coln0 + n * 16;
                        float v0, v1, v2, v3;
                        if (coln + 3 < Ncols) {
                            const float4 b4 = *(const float4*)&bias[coln];
                            v0 = acc[m][n][0] + b4.x; v1 = acc[m][n][1] + b4.y;
                            v2 = acc[m][n][2] + b4.z; v3 = acc[m][n][3] + b4.w;
                            se += __expf(v0) + __expf(v1) + __expf(v2) + __expf(v3);
                        } else {
                            float vv[4];
#pragma unroll
                            for (int e = 0; e < 4; e++) {
                                int col = coln + e;
                                float v = (col < Ncols) ? acc[m][n][e] + bias[col] : 0.f;
                                vv[e] = v;
                                if (col < Ncols) se += __expf(v);
                            }
                            v0 = vv[0]; v1 = vv[1]; v2 = vv[2]; v3 = vv[3];
                        }
                        float* p = &LDSf[lrow * 133 + wn * 64 + lg * 4 + n * 16];
                        p[0] = v0; p[1] = v1; p[2] = v2; p[3] = v3;
                    }
                    se += __shfl_xor(se, 16);
                    se += __shfl_xor(se, 32);
                    if (lg == 0)
                        __builtin_nontemporal_store(se, &pbuf[(size_t)row * PSTRIDE + ptile]);
                }
            }
            __builtin_amdgcn_s_barrier();
#pragma unroll
            for (int it = 0; it < 8; ++it) {
                const int lrow = it * 8 + lr0;
                const int grow = bm + h * 64 + lrow;
                const int col = bn + lc;
                f32x4 v;
                v[0] = LDSf[lrow * 133 + lc + 0];
                v[1] = LDSf[lrow * 133 + lc + 1];
                v[2] = LDSf[lrow * 133 + lc + 2];
                v[3] = LDSf[lrow * 133 + lc + 3];
                if (col + 3 < Ncols) {
                    __builtin_nontemporal_store(v, (f32x4*)&C[(size_t)grow * Ncols + col]);
                } else {
#pragma unroll
                    for (int e = 0; e < 4; e++)
                        if (col + e < Ncols)
                            __builtin_nontemporal_store(v[e], &C[(size_t)grow * Ncols + col + e]);
                }
            }
        }
    }
}

// ---------------- MFMA flash attention (paired q-tiles for load balance) ----------------
// grid (4, 128): block p handles q-tiles p and 7-p -> every block = 9 k-tiles.
__global__ __launch_bounds__(256) void attn_kernel(
    const bf16_t* __restrict__ qkvb, const bf16_t* __restrict__ vt,
    bf16_t* __restrict__ o)
{
    const int bh = blockIdx.y;
    const int b = bh >> 3, h = bh & 7;
    __shared__ unsigned short psm[4608];
    const int tid = threadIdx.x;
    const int w = tid >> 6, lane = tid & 63;
    const int ll = lane & 15, g = lane >> 4;

    const bf16_t* kptr = qkvb + (size_t)b * 512 * 1152 + 384 + h * 48;
    const bf16_t* vptr = vt + (size_t)b * 384 * 512 + (size_t)h * 48 * 512;

    auto runQ = [&](int qt) {
        const int q0 = qt * 64;
        const int q_abs = q0 + ll * 4 + w;

        const bf16_t* qrow = qkvb + (size_t)(b * 512 + q_abs) * 1152 + h * 48;
        bf16x8 qf0 = __builtin_bit_cast(bf16x8, *(const s16x8*)(qrow + g * 8));
        bf16x8 qf1 = {};
        if (g < 2) qf1 = __builtin_bit_cast(bf16x8, *(const s16x8*)(qrow + 32 + g * 8));

        f32x4 oacc[3];
#pragma unroll
        for (int df = 0; df < 3; df++) oacc[df] = (f32x4){0.f, 0.f, 0.f, 0.f};
        float ssum = 0.f;
        const int ntiles = 2 * (qt + 1);

        auto loadK = [&](int kbase, bf16x8& c00, bf16x8& c01, bf16x8& c10, bf16x8& c11) {
            const bf16_t* kr0 = kptr + (size_t)(kbase + ll) * 1152;
            const bf16_t* kr1 = kptr + (size_t)(kbase + 16 + ll) * 1152;
            c00 = __builtin_bit_cast(bf16x8, *(const s16x8*)(kr0 + g * 8));
            c10 = __builtin_bit_cast(bf16x8, *(const s16x8*)(kr1 + g * 8));
            bf16x8 z = {};
            c01 = (g < 2) ? __builtin_bit_cast(bf16x8, *(const s16x8*)(kr0 + 32 + g * 8)) : z;
            c11 = (g < 2) ? __builtin_bit_cast(bf16x8, *(const s16x8*)(kr1 + 32 + g * 8)) : z;
        };

        auto doTile = [&](int kbase, int parity,
                          const bf16x8& c00, const bf16x8& c01, const bf16x8& c10, const bf16x8& c11,
                          bool pf, int nbase,
                          bf16x8& n00, bf16x8& n01, bf16x8& n10, bf16x8& n11) {
            bf16x8 vf[3];
#pragma unroll
            for (int df = 0; df < 3; df++)
                vf[df] = __builtin_bit_cast(bf16x8,
                    *(const s16x8*)(vptr + (size_t)(df * 16 + ll) * 512 + kbase + g * 8));
            if (pf) loadK(nbase, n00, n01, n10, n11);

            f32x4 sfr[2];
            {
                f32x4 z0 = {0.f, 0.f, 0.f, 0.f};
                z0 = __builtin_amdgcn_mfma_f32_16x16x32_bf16(c00, qf0, z0, 0, 0, 0);
                z0 = __builtin_amdgcn_mfma_f32_16x16x32_bf16(c01, qf1, z0, 0, 0, 0);
                sfr[0] = z0;
                f32x4 z1 = {0.f, 0.f, 0.f, 0.f};
                z1 = __builtin_amdgcn_mfma_f32_16x16x32_bf16(c10, qf0, z1, 0, 0, 0);
                z1 = __builtin_amdgcn_mfma_f32_16x16x32_bf16(c11, qf1, z1, 0, 0, 0);
                sfr[1] = z1;
            }

            float p[8];
#pragma unroll
            for (int f = 0; f < 2; f++)
#pragma unroll
                for (int j = 0; j < 4; j++) {
                    int key = kbase + f * 16 + g * 4 + j;
                    float sv = sfr[f][j];
                    sv = (key > q_abs) ? -1e30f : sv;
                    float pv = __expf(fminf(sv, 20.f));
                    p[f * 4 + j] = pv;
                    ssum += pv;
                }

            const int pbase = (w * 2 + parity) * 576;
#pragma unroll
            for (int f = 0; f < 2; f++)
#pragma unroll
                for (int j = 0; j < 4; j++)
                    psm[pbase + (f * 16 + g * 4 + j) * 18 + ll] = bf16bits(p[f * 4 + j]);
            s16x8 pr;
#pragma unroll
            for (int i = 0; i < 8; i++)
                pr[i] = (short)psm[pbase + (g * 8 + i) * 18 + ll];
            bf16x8 pfr = __builtin_bit_cast(bf16x8, pr);
#pragma unroll
            for (int df = 0; df < 3; df++)
                oacc[df] = __builtin_amdgcn_mfma_f32_16x16x32_bf16(vf[df], pfr, oacc[df], 0, 0, 0);
        };

        bf16x8 kA0, kA1, kA2, kA3, kB0, kB1, kB2, kB3;
        loadK(0, kA0, kA1, kA2, kA3);
        for (int kt = 0; kt < ntiles; kt += 2) {
            doTile(kt * 32, 0, kA0, kA1, kA2, kA3,
                   true, (kt + 1) * 32, kB0, kB1, kB2, kB3);
            doTile((kt + 1) * 32, 1, kB0, kB1, kB2, kB3,
                   (kt + 2) < ntiles, (kt + 2) * 32, kA0, kA1, kA2, kA3);
        }

        ssum += __shfl_xor(ssum, 16);
        ssum += __shfl_xor(ssum, 32);
        float inv = 1.f / ssum;
        bf16_t* orow = o + (size_t)(b * 512 + q_abs) * 384 + h * 48;
#pragma unroll
        for (int df = 0; df < 3; df++) {
            ushort4 pk;
            pk.x = bf16bits(oacc[df][0] * inv);
            pk.y = bf16bits(oacc[df][1] * inv);
            pk.z = bf16bits(oacc[df][2] * inv);
            pk.w = bf16bits(oacc[df][3] * inv);
            *(ushort4*)&orow[df * 16 + g * 4] = pk;
        }
    };

    runQ(blockIdx.x);        // short tile (1..4 k-pairs)
    runQ(7 - blockIdx.x);    // long tile  -> every block totals 9 k-tiles
}

// ---------------- loss from fused partials ----------------
__global__ __launch_bounds__(256) void loss_row2_kernel(
    const float* __restrict__ pbuf, const float* __restrict__ logits,
    const int* __restrict__ targets, float* __restrict__ rowloss)
{
    int row = blockIdx.x * 4 + (threadIdx.x >> 6);
    int lane = threadIdx.x & 63;
    const float* pr = pbuf + (size_t)row * PSTRIDE;
    float s = 0.f;
    for (int i = lane; i < NPART; i += 64) s += pr[i];
#pragma unroll
    for (int off = 1; off < 64; off <<= 1) s += __shfl_xor(s, off);
    if (lane == 0) {
        int tgt = targets[row];
        rowloss[row] = logf(s) - logits[(size_t)row * V_DIM + tgt];
    }
}

__global__ __launch_bounds__(256) void loss_reduce_kernel(
    const float* __restrict__ rowloss, float* __restrict__ out)
{
    int t = threadIdx.x;
    __shared__ float red[4];
    float s = 0.f;
    for (int i = t; i < M_ROWS; i += 256) s += rowloss[i];
#pragma unroll
    for (int off = 1; off < 64; off <<= 1) s += __shfl_xor(s, off);
    if ((t & 63) == 0) red[t >> 6] = s;
    __syncthreads();
    if (t == 0) out[0] = (red[0] + red[1] + red[2] + red[3]) * (1.f / M_ROWS);
}

// ---------------- launch ----------------
extern "C" void kernel_launch(void* const* d_in, const int* in_sizes, int n_in,
                              void* d_out, int out_size, void* d_ws, size_t ws_size,
                              hipStream_t stream)
{
    const int*   index   = (const int*)d_in[0];
    const int*   targets = (const int*)d_in[1];
    const float* tok_emb = (const float*)d_in[2];
    const float* pos_emb = (const float*)d_in[3];
    const float* Wq = (const float*)d_in[4];
    const float* bq = (const float*)d_in[5];
    const float* Wk = (const float*)d_in[6];
    const float* bk = (const float*)d_in[7];
    const float* Wv = (const float*)d_in[8];
    const float* bv = (const float*)d_in[9];
    const float* Wo = (const float*)d_in[10];
    const float* bo = (const float*)d_in[11];
    const float* ln1_g = (const float*)d_in[12];
    const float* ln1_b = (const float*)d_in[13];
    const float* ln2_g = (const float*)d_in[14];
    const float* ln2_b = (const float*)d_in[15];
    const float* W1 = (const float*)d_in[16];
    const float* b1 = (const float*)d_in[17];
    const float* W2 = (const float*)d_in[18];
    const float* b2 = (const float*)d_in[19];
    const float* lnf_g = (const float*)d_in[20];
    const float* lnf_b = (const float*)d_in[21];
    const float* lm_b  = (const float*)d_in[22];

    float* out = (float*)d_out;
    char* wsb = (char*)d_ws;

    // workspace layout (bytes)
    float*  x     = (float*)(wsb + 0);              // [8192][384] f32
    bf16_t* hbuf  = (bf16_t*)(wsb + 12582912);      // [8192][384] bf16
    bf16_t* obuf  = (bf16_t*)(wsb + 18874368);      // [8192][384] bf16
    bf16_t* qkvb  = (bf16_t*)(wsb + 25165824);      // [8192][1152] bf16
    bf16_t* vtb   = (bf16_t*)(wsb + 44040192);      // [16][384][512] bf16
    bf16_t* ffmid = (bf16_t*)(wsb + 18874368);      // aliases obuf+qkvb
    float*  pbuf  = (float*)(wsb + 25165824);       // aliases qkvb (dead at logits): [8192][320]
    bf16_t* tokb  = (bf16_t*)(wsb + 50331648);      // [20096][384] bf16
    bf16_t* qkvw  = (bf16_t*)(wsb + 65765376);      // [8][1152][384] bf16
    bf16_t* wo_t  = (bf16_t*)(wsb + 72843264);      // [8][384][384]
    bf16_t* w1_t  = (bf16_t*)(wsb + 75202560);      // [8][1536][384]
    bf16_t* w2_t  = (bf16_t*)(wsb + 84639744);      // [8][384][1536]
    float*  bqkv  = (float*)(wsb + 94076928);       // [8][1152] f32
    float*  rowloss = (float*)(wsb + 94113792);     // [8192]

    // ---- weight prep ----
    tokconv_kernel<<<2048, 256, 0, stream>>>(tok_emb, tokb);
    tconv_kernel<<<dim3(12, 12, 8), 256, 0, stream>>>(Wq, qkvw, 384, 384, 1152, 0);
    tconv_kernel<<<dim3(12, 12, 8), 256, 0, stream>>>(Wk, qkvw, 384, 384, 1152, 384);
    tconv_kernel<<<dim3(12, 12, 8), 256, 0, stream>>>(Wv, qkvw, 384, 384, 1152, 768);
    tconv_kernel<<<dim3(12, 12, 8), 256, 0, stream>>>(Wo, wo_t, 384, 384, 384, 0);
    tconv_kernel<<<dim3(48, 12, 8), 256, 0, stream>>>(W1, w1_t, 384, 1536, 1536, 0);
    tconv_kernel<<<dim3(12, 48, 8), 256, 0, stream>>>(W2, w2_t, 1536, 384, 384, 0);
    bqkv_kernel<<<36, 256, 0, stream>>>(bq, bk, bv, bqkv);

    embed_kernel<<<2048, 256, 0, stream>>>(index, tok_emb, pos_emb, x);

    for (int l = 0; l < N_LAYER; l++) {
        const bf16_t* qkvw_l = qkvw + (size_t)l * 1152 * 384;
        const float*  bqkv_l = bqkv + l * 1152;
        ln_kernel<<<2048, 256, 0, stream>>>(x, ln1_g + l * E_DIM, ln1_b + l * E_DIM, hbuf);
        gemm_kernel<4, 4><<<dim3(9, 64), 256, 0, stream>>>(
            hbuf, qkvw_l, bqkv_l, qkvb, vtb, 1152, 384);
        attn_kernel<<<dim3(4, 128), 256, 0, stream>>>(qkvb, vtb, obuf);
        gemm_kernel<1, 2><<<dim3(3, 128), 256, 0, stream>>>(
            obuf, wo_t + (size_t)l * 384 * 384, bo + l * E_DIM, x, nullptr, 384, 384);
        ln_kernel<<<2048, 256, 0, stream>>>(x, ln2_g + l * E_DIM, ln2_b + l * E_DIM, hbuf);
        gemm_kernel<2, 4><<<dim3(12, 64), 256, 0, stream>>>(
            hbuf, w1_t + (size_t)l * 1536 * 384, b1 + l * FF_DIM, ffmid, nullptr, 1536, 384);
        gemm_kernel<1, 2><<<dim3(3, 128), 256, 0, stream>>>(
            ffmid, w2_t + (size_t)l * 384 * 1536, b2 + l * E_DIM, x, nullptr, 384, 1536);
    }

    ln_kernel<<<2048, 256, 0, stream>>>(x, lnf_g, lnf_b, hbuf);
    gemm_kernel<3, 4><<<dim3(64, 157), 256, 0, stream>>>(
        hbuf, tokb, lm_b, out, pbuf, V_DIM, 384);

    loss_row2_kernel<<<2048, 256, 0, stream>>>(pbuf, out, targets, rowloss);
    loss_reduce_kernel<<<1, 256, 0, stream>>>(rowloss, out + (size_t)M_ROWS * V_DIM);
}

// Round 18
// 1639.732 us; speedup vs baseline: 1.0275x; 1.0275x over previous
//
#include <hip/hip_runtime.h>
#include <hip/hip_bf16.h>
#include <math.h>

// B=16, T=512, E=384, H=8, D=48, L=8, V=20000, FF=1536, M = B*T = 8192
#define M_ROWS 8192
#define E_DIM 384
#define FF_DIM 1536
#define V_DIM 20000
#define VPAD 20096   // 157 * 128
#define N_LAYER 8
#define QK_SCALE 0.14433756729740643f
#define PSTRIDE 160   // padded 157 partials per row
#define NPART 157

typedef __bf16 bf16x8 __attribute__((ext_vector_type(8)));
typedef short  s16x8  __attribute__((ext_vector_type(8)));
typedef float  f32x4  __attribute__((ext_vector_type(4)));
typedef __hip_bfloat16 bf16_t;

__device__ __forceinline__ void gl2lds16(const void* g, void* l) {
    __builtin_amdgcn_global_load_lds((const __attribute__((address_space(1))) void*)g,
                                     (__attribute__((address_space(3))) void*)l, 16, 0, 0);
}
__device__ __forceinline__ unsigned short bf16bits(float v) {
    return __builtin_bit_cast(unsigned short, __float2bfloat16(v));
}

// ---------------- weight prep ----------------
__global__ __launch_bounds__(256) void tconv_kernel(
    const float* __restrict__ in, bf16_t* __restrict__ out,
    int K, int N, int outRows, int rowoff)
{
    __shared__ float tile[32][33];
    const int n0 = blockIdx.x * 32, k0 = blockIdx.y * 32;
    const float* ip = in + (size_t)blockIdx.z * K * N;
    bf16_t* op = out + (size_t)blockIdx.z * outRows * K;
    const int tx = threadIdx.x & 31, ty = threadIdx.x >> 5;
#pragma unroll
    for (int i = 0; i < 32; i += 8)
        tile[ty + i][tx] = ip[(size_t)(k0 + ty + i) * N + n0 + tx];
    __syncthreads();
#pragma unroll
    for (int i = 0; i < 32; i += 8)
        op[(size_t)(rowoff + n0 + ty + i) * K + k0 + tx] = __float2bfloat16(tile[tx][ty + i]);
}

__global__ __launch_bounds__(256) void tokconv_kernel(
    const float* __restrict__ tok, bf16_t* __restrict__ out)
{
    const int total = VPAD * 48;  // groups of 8 cols
    for (int idx = blockIdx.x * 256 + threadIdx.x; idx < total; idx += gridDim.x * 256) {
        int row = idx / 48, gc = idx - row * 48;
        int col = gc * 8;
        s16x8 pk = {};
        if (row < V_DIM) {
            const float* tp = tok + (size_t)row * E_DIM + col;
            float4 f0 = *(const float4*)tp;
            float4 f1 = *(const float4*)(tp + 4);
            pk[0] = (short)bf16bits(f0.x); pk[1] = (short)bf16bits(f0.y);
            pk[2] = (short)bf16bits(f0.z); pk[3] = (short)bf16bits(f0.w);
            pk[4] = (short)bf16bits(f1.x); pk[5] = (short)bf16bits(f1.y);
            pk[6] = (short)bf16bits(f1.z); pk[7] = (short)bf16bits(f1.w);
        }
        *(s16x8*)&out[(size_t)row * E_DIM + col] = pk;
    }
}

__global__ __launch_bounds__(256) void bqkv_kernel(
    const float* __restrict__ bq, const float* __restrict__ bk,
    const float* __restrict__ bv, float* __restrict__ o)
{
    int i = blockIdx.x * 256 + threadIdx.x;
    if (i < N_LAYER * 1152) {
        int l = i / 1152, c = i - l * 1152;
        float v = (c < 384) ? bq[l * 384 + c] : (c < 768) ? bk[l * 384 + c - 384] : bv[l * 384 + c - 768];
        o[i] = v;
    }
}

// ---------------- embedding ----------------
__global__ __launch_bounds__(256) void embed_kernel(
    const int* __restrict__ idx, const float* __restrict__ tok,
    const float* __restrict__ pos, float* __restrict__ x)
{
    int row = blockIdx.x * 4 + (threadIdx.x >> 6);
    int lane = threadIdx.x & 63;
    int t = row & 511;
    int id = idx[row];
    const float* tr = tok + (size_t)id * E_DIM;
    const float* pr = pos + (size_t)t * E_DIM;
    float* xr = x + (size_t)row * E_DIM;
#pragma unroll
    for (int i = 0; i < 6; i++) { int c = lane + i * 64; xr[c] = tr[c] + pr[c]; }
}

// ---------------- layernorm -> bf16 ----------------
__global__ __launch_bounds__(256) void ln_kernel(
    const float* __restrict__ x, const float* __restrict__ g,
    const float* __restrict__ b, bf16_t* __restrict__ out)
{
    int row = blockIdx.x * 4 + (threadIdx.x >> 6);
    int lane = threadIdx.x & 63;
    const float* xr = x + (size_t)row * E_DIM;
    float vals[6];
    float s = 0.f;
#pragma unroll
    for (int i = 0; i < 6; i++) { vals[i] = xr[lane + i * 64]; s += vals[i]; }
#pragma unroll
    for (int off = 1; off < 64; off <<= 1) s += __shfl_xor(s, off);
    float mu = s * (1.f / E_DIM);
    float sq = 0.f;
#pragma unroll
    for (int i = 0; i < 6; i++) { float d = vals[i] - mu; sq += d * d; }
#pragma unroll
    for (int off = 1; off < 64; off <<= 1) sq += __shfl_xor(sq, off);
    float rstd = rsqrtf(sq * (1.f / E_DIM) + 1e-5f);
    bf16_t* orow = out + (size_t)row * E_DIM;
#pragma unroll
    for (int i = 0; i < 6; i++) {
        int c = lane + i * 64;
        orow[c] = __float2bfloat16((vals[i] - mu) * rstd * g[c] + b[c]);
    }
}

// ---------------- bf16 MFMA GEMM (3-buffer, counted-vmcnt pipeline) ----------------
// MODE 1: fp32 out += C (residual)  MODE 2: bf16 out, GELU  MODE 4: QKV epilogue
template <int MODE, int MREP>
__global__ __launch_bounds__(256) void gemm_kernel(
    const bf16_t* __restrict__ A, const bf16_t* __restrict__ Bt,
    const float* __restrict__ bias, void* __restrict__ Cv, void* __restrict__ C2,
    int Ncols, int K)
{
    constexpr int BMR = MREP * 32;
    constexpr int ASH = BMR * 32;
    constexpr int BUFSH = ASH + 4096;
    constexpr int NLD = MREP / 2 + 2;
    __shared__ __align__(16) short smem[3 * BUFSH];
    const int t = threadIdx.x;
    const int w = t >> 6, lane = t & 63;
    const int wm = w >> 1, wn = w & 1;
    const int bm = blockIdx.y * BMR;
    const int bn = blockIdx.x * 128;

    f32x4 acc[MREP][4];
#pragma unroll
    for (int m = 0; m < MREP; m++)
#pragma unroll
        for (int n = 0; n < 4; n++)
            acc[m][n] = (f32x4){0.f, 0.f, 0.f, 0.f};

    const int lg = lane >> 4;
    const int ll = lane & 15;
    const int nt = K / 32;

    auto stagef = [&](int kt, int buf) {
        short* sA = smem + buf * BUFSH;
        short* sB = sA + ASH;
#pragma unroll
        for (int i = 0; i < MREP / 2; i++) {
            int li = i * 256 + t;
            int g = li >> (MREP == 4 ? 7 : 6);
            int row = li & (BMR - 1);
            gl2lds16(A + (size_t)(bm + row) * K + kt + g * 8,
                     sA + (size_t)(i * 256 + w * 64) * 8);
        }
#pragma unroll
        for (int i = 0; i < 2; i++) {
            int li = i * 256 + t;
            gl2lds16(Bt + (size_t)(bn + (li & 127)) * K + kt + (li >> 7) * 8,
                     sB + (size_t)(i * 256 + w * 64) * 8);
        }
    };

    stagef(0, 0);
    stagef(32, 1);

    for (int tt = 0; tt < nt; ++tt) {
        if (tt + 2 < nt) {
            stagef((tt + 2) * 32, (tt + 2) % 3);
            asm volatile("s_waitcnt vmcnt(%0)" :: "n"(2 * NLD) : "memory");
        } else if (tt + 1 < nt) {
            asm volatile("s_waitcnt vmcnt(%0)" :: "n"(NLD) : "memory");
        } else {
            asm volatile("s_waitcnt vmcnt(0)" ::: "memory");
        }
        __builtin_amdgcn_s_barrier();

        const short* sA = smem + (tt % 3) * BUFSH;
        const short* sB = sA + ASH;
        bf16x8 af[MREP], bfr[4];
#pragma unroll
        for (int m = 0; m < MREP; m++)
            af[m] = __builtin_bit_cast(bf16x8,
                *(const s16x8*)&sA[(lg * BMR + wm * (BMR / 2) + m * 16 + ll) * 8]);
#pragma unroll
        for (int n = 0; n < 4; n++)
            bfr[n] = __builtin_bit_cast(bf16x8,
                *(const s16x8*)&sB[(lg * 128 + wn * 64 + n * 16 + ll) * 8]);
#pragma unroll
        for (int m = 0; m < MREP; m++)
#pragma unroll
            for (int n = 0; n < 4; n++)
                acc[m][n] = __builtin_amdgcn_mfma_f32_16x16x32_bf16(bfr[n], af[m], acc[m][n], 0, 0, 0);

        __builtin_amdgcn_s_barrier();
    }

    const int rowm0 = bm + wm * (BMR / 2) + ll;
    const int coln0 = bn + wn * 64 + lg * 4;

    if constexpr (MODE == 4) {
        if (bn < 768) {
            bf16_t* qkvb = (bf16_t*)Cv;
            const float sc = (bn >= 384) ? 1.f : QK_SCALE;
#pragma unroll
            for (int n = 0; n < 4; n++) {
                const int coln = coln0 + n * 16;
                const float4 b4 = *(const float4*)&bias[coln];
#pragma unroll
                for (int m = 0; m < MREP; m++) {
                    const int row = rowm0 + m * 16;
                    ushort4 pk;
                    pk.x = bf16bits((acc[m][n][0] + b4.x) * sc);
                    pk.y = bf16bits((acc[m][n][1] + b4.y) * sc);
                    pk.z = bf16bits((acc[m][n][2] + b4.z) * sc);
                    pk.w = bf16bits((acc[m][n][3] + b4.w) * sc);
                    *(ushort4*)&qkvb[(size_t)row * 1152 + coln] = pk;
                }
            }
        } else {
            bf16_t* vtb = (bf16_t*)C2;
            const int cc0 = coln0 - 768;
#pragma unroll
            for (int n = 0; n < 4; n++) {
                const float4 b4 = *(const float4*)&bias[coln0 + n * 16];
#pragma unroll
                for (int m = 0; m < MREP; m++) {
                    const int row = rowm0 + m * 16;
                    const int bb = row >> 9, tt2 = row & 511;
                    bf16_t* vb = vtb + (size_t)bb * 384 * 512 + tt2;
                    vb[(size_t)(cc0 + n * 16 + 0) * 512] = __float2bfloat16(acc[m][n][0] + b4.x);
                    vb[(size_t)(cc0 + n * 16 + 1) * 512] = __float2bfloat16(acc[m][n][1] + b4.y);
                    vb[(size_t)(cc0 + n * 16 + 2) * 512] = __float2bfloat16(acc[m][n][2] + b4.z);
                    vb[(size_t)(cc0 + n * 16 + 3) * 512] = __float2bfloat16(acc[m][n][3] + b4.w);
                }
            }
        }
    } else if constexpr (MODE == 1) {
        float* C = (float*)Cv;
#pragma unroll
        for (int n = 0; n < 4; n++) {
            const int coln = coln0 + n * 16;
            const float4 b4 = *(const float4*)&bias[coln];
#pragma unroll
            for (int m = 0; m < MREP; m++) {
                const int row = rowm0 + m * 16;
                float4 cv = *(float4*)&C[(size_t)row * Ncols + coln];
                cv.x += acc[m][n][0] + b4.x;
                cv.y += acc[m][n][1] + b4.y;
                cv.z += acc[m][n][2] + b4.z;
                cv.w += acc[m][n][3] + b4.w;
                *(float4*)&C[(size_t)row * Ncols + coln] = cv;
            }
        }
    } else if constexpr (MODE == 2) {
        bf16_t* O = (bf16_t*)Cv;
#pragma unroll
        for (int n = 0; n < 4; n++) {
            const int coln = coln0 + n * 16;
            const float4 b4 = *(const float4*)&bias[coln];
#pragma unroll
            for (int m = 0; m < MREP; m++) {
                const int row = rowm0 + m * 16;
                float v0 = acc[m][n][0] + b4.x, v1 = acc[m][n][1] + b4.y;
                float v2 = acc[m][n][2] + b4.z, v3 = acc[m][n][3] + b4.w;
                v0 = 0.5f * v0 * (1.f + erff(v0 * 0.70710678118654752f));
                v1 = 0.5f * v1 * (1.f + erff(v1 * 0.70710678118654752f));
                v2 = 0.5f * v2 * (1.f + erff(v2 * 0.70710678118654752f));
                v3 = 0.5f * v3 * (1.f + erff(v3 * 0.70710678118654752f));
                ushort4 pk;
                pk.x = bf16bits(v0); pk.y = bf16bits(v1);
                pk.z = bf16bits(v2); pk.w = bf16bits(v3);
                *(ushort4*)&O[(size_t)row * Ncols + coln] = pk;
            }
        }
    }
}

// ---------------- logits GEMM: A-register-resident, B-streamed ----------------
// grid (64, 8). Block = 4 waves; wave owns 32 rows (A slice in 96 VGPRs, loaded
// once). Sweeps ~20 bn-tiles of 128 cols; B streams through 3x8KB LDS buffers
// with counted vmcnt; pipeline continuous across tiles (12 steps % 3 bufs == 0).
__global__ __launch_bounds__(256) void logits_kernel(
    const bf16_t* __restrict__ A, const bf16_t* __restrict__ Bt,
    const float* __restrict__ bias, float* __restrict__ C,
    float* __restrict__ pbuf)
{
    __shared__ __align__(16) short smem[3 * 4096];   // 3 x 8KB B buffers
    const int t = threadIdx.x;
    const int w = t >> 6, lane = t & 63;
    const int lg = lane >> 4, ll = lane & 15;
    const int bm = blockIdx.x * 128;
    const int wr = bm + w * 32;                       // wave's 32-row base
    const int tstart = (blockIdx.y * 157) >> 3;
    const int tend = ((blockIdx.y + 1) * 157) >> 3;

    // A-resident fragments: af[kt][m], row = wr + m*16 + ll, k = kt*32 + lg*8
    bf16x8 af[12][2];
#pragma unroll
    for (int kt = 0; kt < 12; kt++)
#pragma unroll
        for (int m = 0; m < 2; m++)
            af[kt][m] = __builtin_bit_cast(bf16x8,
                *(const s16x8*)(A + (size_t)(wr + m * 16 + ll) * E_DIM + kt * 32 + lg * 8));

    auto stageB = [&](int tile, int kt, int buf) {
        short* sB = smem + buf * 4096;
#pragma unroll
        for (int i = 0; i < 2; i++) {
            int li = i * 256 + t;
            gl2lds16(Bt + (size_t)(tile * 128 + (li & 127)) * E_DIM + kt * 32 + (li >> 7) * 8,
                     sB + (size_t)(i * 256 + w * 64) * 8);
        }
    };

    stageB(tstart, 0, 0);
    stageB(tstart, 1, 1);

    for (int tile = tstart; tile < tend; ++tile) {
        f32x4 acc[2][8];
#pragma unroll
        for (int m = 0; m < 2; m++)
#pragma unroll
            for (int n = 0; n < 8; n++)
                acc[m][n] = (f32x4){0.f, 0.f, 0.f, 0.f};

#pragma unroll
        for (int kt = 0; kt < 12; ++kt) {
            // prefetch step kt+2 (possibly into next tile); counted waits
            const int sleft = (tend - 1 - tile) * 12 + (11 - kt);
            if (kt + 2 < 12) {
                stageB(tile, kt + 2, (kt + 2) % 3);
                asm volatile("s_waitcnt vmcnt(4)" ::: "memory");
            } else if (tile + 1 < tend) {
                stageB(tile + 1, kt + 2 - 12, (kt + 2) % 3);
                asm volatile("s_waitcnt vmcnt(4)" ::: "memory");
            } else if (sleft >= 1) {
                asm volatile("s_waitcnt vmcnt(2)" ::: "memory");
            } else {
                asm volatile("s_waitcnt vmcnt(0)" ::: "memory");
            }
            __builtin_amdgcn_s_barrier();

            const short* sB = smem + (kt % 3) * 4096;
            bf16x8 bfr[8];
#pragma unroll
            for (int n = 0; n < 8; n++)
                bfr[n] = __builtin_bit_cast(bf16x8,
                    *(const s16x8*)&sB[(lg * 128 + n * 16 + ll) * 8]);
#pragma unroll
            for (int m = 0; m < 2; m++)
#pragma unroll
                for (int n = 0; n < 8; n++)
                    acc[m][n] = __builtin_amdgcn_mfma_f32_16x16x32_bf16(
                        bfr[n], af[kt][m], acc[m][n], 0, 0, 0);

            __builtin_amdgcn_s_barrier();
        }

        // epilogue: rows wr + m*16 + ll ; cols tile*128 + n*16 + lg*4 + {0..3}
        const int tc = tile * 128;
#pragma unroll
        for (int m = 0; m < 2; m++) {
            const int row = wr + m * 16 + ll;
            float se = 0.f;
#pragma unroll
            for (int n = 0; n < 8; n++) {
                const int coln = tc + n * 16 + lg * 4;
                if (coln + 3 < V_DIM) {
                    const float4 b4 = *(const float4*)&bias[coln];
                    f32x4 v;
                    v[0] = acc[m][n][0] + b4.x;
                    v[1] = acc[m][n][1] + b4.y;
                    v[2] = acc[m][n][2] + b4.z;
                    v[3] = acc[m][n][3] + b4.w;
                    __builtin_nontemporal_store(v, (f32x4*)&C[(size_t)row * V_DIM + coln]);
                    se += __expf(v[0]) + __expf(v[1]) + __expf(v[2]) + __expf(v[3]);
                } else {
#pragma unroll
                    for (int e = 0; e < 4; e++) {
                        int col = coln + e;
                        if (col < V_DIM) {
                            float v = acc[m][n][e] + bias[col];
                            __builtin_nontemporal_store(v, &C[(size_t)row * V_DIM + col]);
                            se += __expf(v);
                        }
                    }
                }
            }
            se += __shfl_xor(se, 16);
            se += __shfl_xor(se, 32);
            if (lg == 0)
                __builtin_nontemporal_store(se, &pbuf[(size_t)row * PSTRIDE + tile]);
        }
    }
}

// ---------------- MFMA flash attention (paired q-tiles for load balance) ----------------
// grid (4, 128): block p handles q-tiles p and 7-p -> every block = 9 k-tiles.
__global__ __launch_bounds__(256) void attn_kernel(
    const bf16_t* __restrict__ qkvb, const bf16_t* __restrict__ vt,
    bf16_t* __restrict__ o)
{
    const int bh = blockIdx.y;
    const int b = bh >> 3, h = bh & 7;
    __shared__ unsigned short psm[4608];
    const int tid = threadIdx.x;
    const int w = tid >> 6, lane = tid & 63;
    const int ll = lane & 15, g = lane >> 4;

    const bf16_t* kptr = qkvb + (size_t)b * 512 * 1152 + 384 + h * 48;
    const bf16_t* vptr = vt + (size_t)b * 384 * 512 + (size_t)h * 48 * 512;

    auto runQ = [&](int qt) {
        const int q0 = qt * 64;
        const int q_abs = q0 + ll * 4 + w;

        const bf16_t* qrow = qkvb + (size_t)(b * 512 + q_abs) * 1152 + h * 48;
        bf16x8 qf0 = __builtin_bit_cast(bf16x8, *(const s16x8*)(qrow + g * 8));
        bf16x8 qf1 = {};
        if (g < 2) qf1 = __builtin_bit_cast(bf16x8, *(const s16x8*)(qrow + 32 + g * 8));

        f32x4 oacc[3];
#pragma unroll
        for (int df = 0; df < 3; df++) oacc[df] = (f32x4){0.f, 0.f, 0.f, 0.f};
        float ssum = 0.f;
        const int ntiles = 2 * (qt + 1);

        auto loadK = [&](int kbase, bf16x8& c00, bf16x8& c01, bf16x8& c10, bf16x8& c11) {
            const bf16_t* kr0 = kptr + (size_t)(kbase + ll) * 1152;
            const bf16_t* kr1 = kptr + (size_t)(kbase + 16 + ll) * 1152;
            c00 = __builtin_bit_cast(bf16x8, *(const s16x8*)(kr0 + g * 8));
            c10 = __builtin_bit_cast(bf16x8, *(const s16x8*)(kr1 + g * 8));
            bf16x8 z = {};
            c01 = (g < 2) ? __builtin_bit_cast(bf16x8, *(const s16x8*)(kr0 + 32 + g * 8)) : z;
            c11 = (g < 2) ? __builtin_bit_cast(bf16x8, *(const s16x8*)(kr1 + 32 + g * 8)) : z;
        };

        auto doTile = [&](int kbase, int parity,
                          const bf16x8& c00, const bf16x8& c01, const bf16x8& c10, const bf16x8& c11,
                          bool pf, int nbase,
                          bf16x8& n00, bf16x8& n01, bf16x8& n10, bf16x8& n11) {
            bf16x8 vf[3];
#pragma unroll
            for (int df = 0; df < 3; df++)
                vf[df] = __builtin_bit_cast(bf16x8,
                    *(const s16x8*)(vptr + (size_t)(df * 16 + ll) * 512 + kbase + g * 8));
            if (pf) loadK(nbase, n00, n01, n10, n11);

            f32x4 sfr[2];
            {
                f32x4 z0 = {0.f, 0.f, 0.f, 0.f};
                z0 = __builtin_amdgcn_mfma_f32_16x16x32_bf16(c00, qf0, z0, 0, 0, 0);
                z0 = __builtin_amdgcn_mfma_f32_16x16x32_bf16(c01, qf1, z0, 0, 0, 0);
                sfr[0] = z0;
                f32x4 z1 = {0.f, 0.f, 0.f, 0.f};
                z1 = __builtin_amdgcn_mfma_f32_16x16x32_bf16(c10, qf0, z1, 0, 0, 0);
                z1 = __builtin_amdgcn_mfma_f32_16x16x32_bf16(c11, qf1, z1, 0, 0, 0);
                sfr[1] = z1;
            }

            float p[8];
#pragma unroll
            for (int f = 0; f < 2; f++)
#pragma unroll
                for (int j = 0; j < 4; j++) {
                    int key = kbase + f * 16 + g * 4 + j;
                    float sv = sfr[f][j];
                    sv = (key > q_abs) ? -1e30f : sv;
                    float pv = __expf(fminf(sv, 20.f));
                    p[f * 4 + j] = pv;
                    ssum += pv;
                }

            const int pbase = (w * 2 + parity) * 576;
#pragma unroll
            for (int f = 0; f < 2; f++)
#pragma unroll
                for (int j = 0; j < 4; j++)
                    psm[pbase + (f * 16 + g * 4 + j) * 18 + ll] = bf16bits(p[f * 4 + j]);
            s16x8 pr;
#pragma unroll
            for (int i = 0; i < 8; i++)
                pr[i] = (short)psm[pbase + (g * 8 + i) * 18 + ll];
            bf16x8 pfr = __builtin_bit_cast(bf16x8, pr);
#pragma unroll
            for (int df = 0; df < 3; df++)
                oacc[df] = __builtin_amdgcn_mfma_f32_16x16x32_bf16(vf[df], pfr, oacc[df], 0, 0, 0);
        };

        bf16x8 kA0, kA1, kA2, kA3, kB0, kB1, kB2, kB3;
        loadK(0, kA0, kA1, kA2, kA3);
        for (int kt = 0; kt < ntiles; kt += 2) {
            doTile(kt * 32, 0, kA0, kA1, kA2, kA3,
                   true, (kt + 1) * 32, kB0, kB1, kB2, kB3);
            doTile((kt + 1) * 32, 1, kB0, kB1, kB2, kB3,
                   (kt + 2) < ntiles, (kt + 2) * 32, kA0, kA1, kA2, kA3);
        }

        ssum += __shfl_xor(ssum, 16);
        ssum += __shfl_xor(ssum, 32);
        float inv = 1.f / ssum;
        bf16_t* orow = o + (size_t)(b * 512 + q_abs) * 384 + h * 48;
#pragma unroll
        for (int df = 0; df < 3; df++) {
            ushort4 pk;
            pk.x = bf16bits(oacc[df][0] * inv);
            pk.y = bf16bits(oacc[df][1] * inv);
            pk.z = bf16bits(oacc[df][2] * inv);
            pk.w = bf16bits(oacc[df][3] * inv);
            *(ushort4*)&orow[df * 16 + g * 4] = pk;
        }
    };

    runQ(blockIdx.x);        // short tile (1..4 k-pairs)
    runQ(7 - blockIdx.x);    // long tile  -> every block totals 9 k-tiles
}

// ---------------- loss from fused partials ----------------
__global__ __launch_bounds__(256) void loss_row2_kernel(
    const float* __restrict__ pbuf, const float* __restrict__ logits,
    const int* __restrict__ targets, float* __restrict__ rowloss)
{
    int row = blockIdx.x * 4 + (threadIdx.x >> 6);
    int lane = threadIdx.x & 63;
    const float* pr = pbuf + (size_t)row * PSTRIDE;
    float s = 0.f;
    for (int i = lane; i < NPART; i += 64) s += pr[i];
#pragma unroll
    for (int off = 1; off < 64; off <<= 1) s += __shfl_xor(s, off);
    if (lane == 0) {
        int tgt = targets[row];
        rowloss[row] = logf(s) - logits[(size_t)row * V_DIM + tgt];
    }
}

__global__ __launch_bounds__(256) void loss_reduce_kernel(
    const float* __restrict__ rowloss, float* __restrict__ out)
{
    int t = threadIdx.x;
    __shared__ float red[4];
    float s = 0.f;
    for (int i = t; i < M_ROWS; i += 256) s += rowloss[i];
#pragma unroll
    for (int off = 1; off < 64; off <<= 1) s += __shfl_xor(s, off);
    if ((t & 63) == 0) red[t >> 6] = s;
    __syncthreads();
    if (t == 0) out[0] = (red[0] + red[1] + red[2] + red[3]) * (1.f / M_ROWS);
}

// ---------------- launch ----------------
extern "C" void kernel_launch(void* const* d_in, const int* in_sizes, int n_in,
                              void* d_out, int out_size, void* d_ws, size_t ws_size,
                              hipStream_t stream)
{
    const int*   index   = (const int*)d_in[0];
    const int*   targets = (const int*)d_in[1];
    const float* tok_emb = (const float*)d_in[2];
    const float* pos_emb = (const float*)d_in[3];
    const float* Wq = (const float*)d_in[4];
    const float* bq = (const float*)d_in[5];
    const float* Wk = (const float*)d_in[6];
    const float* bk = (const float*)d_in[7];
    const float* Wv = (const float*)d_in[8];
    const float* bv = (const float*)d_in[9];
    const float* Wo = (const float*)d_in[10];
    const float* bo = (const float*)d_in[11];
    const float* ln1_g = (const float*)d_in[12];
    const float* ln1_b = (const float*)d_in[13];
    const float* ln2_g = (const float*)d_in[14];
    const float* ln2_b = (const float*)d_in[15];
    const float* W1 = (const float*)d_in[16];
    const float* b1 = (const float*)d_in[17];
    const float* W2 = (const float*)d_in[18];
    const float* b2 = (const float*)d_in[19];
    const float* lnf_g = (const float*)d_in[20];
    const float* lnf_b = (const float*)d_in[21];
    const float* lm_b  = (const float*)d_in[22];

    float* out = (float*)d_out;
    char* wsb = (char*)d_ws;

    // workspace layout (bytes)
    float*  x     = (float*)(wsb + 0);              // [8192][384] f32
    bf16_t* hbuf  = (bf16_t*)(wsb + 12582912);      // [8192][384] bf16
    bf16_t* obuf  = (bf16_t*)(wsb + 18874368);      // [8192][384] bf16
    bf16_t* qkvb  = (bf16_t*)(wsb + 25165824);      // [8192][1152] bf16
    bf16_t* vtb   = (bf16_t*)(wsb + 44040192);      // [16][384][512] bf16
    bf16_t* ffmid = (bf16_t*)(wsb + 18874368);      // aliases obuf+qkvb
    float*  pbuf  = (float*)(wsb + 25165824);       // aliases qkvb (dead at logits): [8192][160]
    bf16_t* tokb  = (bf16_t*)(wsb + 50331648);      // [20096][384] bf16
    bf16_t* qkvw  = (bf16_t*)(wsb + 65765376);      // [8][1152][384] bf16
    bf16_t* wo_t  = (bf16_t*)(wsb + 72843264);      // [8][384][384]
    bf16_t* w1_t  = (bf16_t*)(wsb + 75202560);      // [8][1536][384]
    bf16_t* w2_t  = (bf16_t*)(wsb + 84639744);      // [8][384][1536]
    float*  bqkv  = (float*)(wsb + 94076928);       // [8][1152] f32
    float*  rowloss = (float*)(wsb + 94113792);     // [8192]

    // ---- weight prep ----
    tokconv_kernel<<<2048, 256, 0, stream>>>(tok_emb, tokb);
    tconv_kernel<<<dim3(12, 12, 8), 256, 0, stream>>>(Wq, qkvw, 384, 384, 1152, 0);
    tconv_kernel<<<dim3(12, 12, 8), 256, 0, stream>>>(Wk, qkvw, 384, 384, 1152, 384);
    tconv_kernel<<<dim3(12, 12, 8), 256, 0, stream>>>(Wv, qkvw, 384, 384, 1152, 768);
    tconv_kernel<<<dim3(12, 12, 8), 256, 0, stream>>>(Wo, wo_t, 384, 384, 384, 0);
    tconv_kernel<<<dim3(48, 12, 8), 256, 0, stream>>>(W1, w1_t, 384, 1536, 1536, 0);
    tconv_kernel<<<dim3(12, 48, 8), 256, 0, stream>>>(W2, w2_t, 1536, 384, 384, 0);
    bqkv_kernel<<<36, 256, 0, stream>>>(bq, bk, bv, bqkv);

    embed_kernel<<<2048, 256, 0, stream>>>(index, tok_emb, pos_emb, x);

    for (int l = 0; l < N_LAYER; l++) {
        const bf16_t* qkvw_l = qkvw + (size_t)l * 1152 * 384;
        const float*  bqkv_l = bqkv + l * 1152;
        ln_kernel<<<2048, 256, 0, stream>>>(x, ln1_g + l * E_DIM, ln1_b + l * E_DIM, hbuf);
        gemm_kernel<4, 4><<<dim3(9, 64), 256, 0, stream>>>(
            hbuf, qkvw_l, bqkv_l, qkvb, vtb, 1152, 384);
        attn_kernel<<<dim3(4, 128), 256, 0, stream>>>(qkvb, vtb, obuf);
        gemm_kernel<1, 2><<<dim3(3, 128), 256, 0, stream>>>(
            obuf, wo_t + (size_t)l * 384 * 384, bo + l * E_DIM, x, nullptr, 384, 384);
        ln_kernel<<<2048, 256, 0, stream>>>(x, ln2_g + l * E_DIM, ln2_b + l * E_DIM, hbuf);
        gemm_kernel<2, 4><<<dim3(12, 64), 256, 0, stream>>>(
            hbuf, w1_t + (size_t)l * 1536 * 384, b1 + l * FF_DIM, ffmid, nullptr, 1536, 384);
        gemm_kernel<1, 2><<<dim3(3, 128), 256, 0, stream>>>(
            ffmid, w2_t + (size_t)l * 384 * 1536, b2 + l * E_DIM, x, nullptr, 384, 1536);
    }

    ln_kernel<<<2048, 256, 0, stream>>>(x, lnf_g, lnf_b, hbuf);
    // logits: A-register-resident, B-streamed, continuous pipeline
    logits_kernel<<<dim3(64, 8), 256, 0, stream>>>(hbuf, tokb, lm_b, out, pbuf);

    loss_row2_kernel<<<2048, 256, 0, stream>>>(pbuf, out, targets, rowloss);
    loss_reduce_kernel<<<1, 256, 0, stream>>>(rowloss, out + (size_t)M_ROWS * V_DIM);
}